// Round 1
// baseline (3597.199 us; speedup 1.0000x reference)
//
#include <hip/hip_runtime.h>
#include <math.h>

// Problem constants
constexpr int Dm = 1024;   // model dim
constexpr int Tt = 2048;   // seq len
constexpr int NB = 2;      // batch
constexpr int NROWS = NB * Tt;  // 4096

#define LN_EPS 1e-5f

// ---------------------------------------------------------------------------
// LayerNorm: one block (256 threads) per row of 1024 floats.
// ---------------------------------------------------------------------------
__global__ __launch_bounds__(256) void ln_kernel(const float* __restrict__ x,
        const float* __restrict__ gamma, const float* __restrict__ beta,
        float* __restrict__ out) {
    const int row = blockIdx.x;
    const int t = threadIdx.x;
    const float* xr = x + (size_t)row * Dm;
    float4 v = *(const float4*)(xr + t * 4);
    float s  = v.x + v.y + v.z + v.w;
    float s2 = v.x * v.x + v.y * v.y + v.z * v.z + v.w * v.w;
    #pragma unroll
    for (int off = 32; off > 0; off >>= 1) {
        s  += __shfl_down(s, off);
        s2 += __shfl_down(s2, off);
    }
    __shared__ float red[8];
    const int wid = t >> 6, lane = t & 63;
    if (lane == 0) { red[wid] = s; red[wid + 4] = s2; }
    __syncthreads();
    if (t == 0) {
        float a = red[0] + red[1] + red[2] + red[3];
        float c = red[4] + red[5] + red[6] + red[7];
        float mean = a * (1.0f / Dm);
        red[0] = mean;
        red[4] = c * (1.0f / Dm) - mean * mean;  // biased var (ddof=0)
    }
    __syncthreads();
    const float mean = red[0];
    const float rstd = rsqrtf(red[4] + LN_EPS);
    float4 gv = *(const float4*)(gamma + t * 4);
    float4 bv = *(const float4*)(beta + t * 4);
    float4 o;
    o.x = (v.x - mean) * rstd * gv.x + bv.x;
    o.y = (v.y - mean) * rstd * gv.y + bv.y;
    o.z = (v.z - mean) * rstd * gv.z + bv.z;
    o.w = (v.w - mean) * rstd * gv.w + bv.w;
    *(float4*)(out + (size_t)row * Dm + t * 4) = o;
}

// ---------------------------------------------------------------------------
// Generic fp32 tiled GEMM: C[M,N] = A[M,K] @ W[K,N] + bias (+ epilogue)
// EPI: 0 = bias only, 1 = bias + residual (res), 2 = bias + exact GELU
// BM=BN=64, BK=16; 256 threads; 4x4 micro-tile per thread.
// ---------------------------------------------------------------------------
__device__ __forceinline__ float gelu_exact(float v) {
    return 0.5f * v * (1.0f + erff(v * 0.70710678118654752f));
}

template<int EPI>
__global__ __launch_bounds__(256) void gemm_kernel(
        const float* __restrict__ A, const float* __restrict__ W,
        const float* __restrict__ bias, const float* __restrict__ res,
        float* __restrict__ C, int M, int N, int K) {
    // As stored transposed [k][m] with stride 68 (multiple of 4 -> aligned
    // float4 reads; 68 mod 32 = 4 banks offset/row, <=2-way conflicts = free)
    __shared__ float As[16][68];
    __shared__ float Ws[16][64];
    const int tid = threadIdx.x;
    const int tx = tid & 15, ty = tid >> 4;
    const int n0 = blockIdx.x * 64, m0 = blockIdx.y * 64;
    const int arow = tid >> 2, ac4 = tid & 3;    // A tile: 64 rows x 4 float4
    const int wrow = tid >> 4, wc4 = tid & 15;   // W tile: 16 rows x 16 float4
    const float* Ap = A + (size_t)(m0 + arow) * K + ac4 * 4;
    const float* Wp = W + (size_t)wrow * N + n0 + wc4 * 4;
    float acc[4][4] = {};
    for (int k0 = 0; k0 < K; k0 += 16) {
        float4 av = *(const float4*)(Ap + k0);
        float4 wv = *(const float4*)(Wp + (size_t)k0 * N);
        __syncthreads();   // protect previous iteration's LDS reads
        As[ac4 * 4 + 0][arow] = av.x;
        As[ac4 * 4 + 1][arow] = av.y;
        As[ac4 * 4 + 2][arow] = av.z;
        As[ac4 * 4 + 3][arow] = av.w;
        *(float4*)&Ws[wrow][wc4 * 4] = wv;
        __syncthreads();
        #pragma unroll
        for (int kk = 0; kk < 16; kk++) {
            float4 a4 = *(const float4*)&As[kk][ty * 4];
            float4 b4 = *(const float4*)&Ws[kk][tx * 4];
            float aa[4] = {a4.x, a4.y, a4.z, a4.w};
            float bb[4] = {b4.x, b4.y, b4.z, b4.w};
            #pragma unroll
            for (int i = 0; i < 4; i++)
                #pragma unroll
                for (int j = 0; j < 4; j++)
                    acc[i][j] = fmaf(aa[i], bb[j], acc[i][j]);
        }
    }
    const float4 bv = *(const float4*)(bias + n0 + tx * 4);
    #pragma unroll
    for (int i = 0; i < 4; i++) {
        const int row = m0 + ty * 4 + i;
        float4 o;
        o.x = acc[i][0] + bv.x;
        o.y = acc[i][1] + bv.y;
        o.z = acc[i][2] + bv.z;
        o.w = acc[i][3] + bv.w;
        if (EPI == 1) {
            float4 r = *(const float4*)(res + (size_t)row * N + n0 + tx * 4);
            o.x += r.x; o.y += r.y; o.z += r.z; o.w += r.w;
        } else if (EPI == 2) {
            o.x = gelu_exact(o.x); o.y = gelu_exact(o.y);
            o.z = gelu_exact(o.z); o.w = gelu_exact(o.w);
        }
        *(float4*)(C + (size_t)row * N + n0 + tx * 4) = o;
    }
}

// ---------------------------------------------------------------------------
// Causal GQA flash attention (fp32 baseline).
// Grid: NB * 16 heads * (Tt/64) q-tiles; block = 64 threads (1 wave).
// Thread t owns q-row qt*64+t: q (64 regs), online softmax (m, l), o[64].
// K/V tiles (64 keys x 64 dims) staged in LDS; compute reads are
// wave-uniform -> LDS broadcast, conflict-free.
// ---------------------------------------------------------------------------
__global__ __launch_bounds__(64) void attn_kernel(
        const float* __restrict__ qb, const float* __restrict__ kb,
        const float* __restrict__ vb, float* __restrict__ ob) {
    const int blk = blockIdx.x;
    const int qt = blk & 31;          // Tt/64 = 32
    const int head = (blk >> 5) & 15;
    const int b = blk >> 9;
    const int g = head >> 2, p = head & 3;
    const int qoff = g * 256 + p * 64;   // q/out column offset for this head
    const int kvoff = g * 64;            // k/v column offset for this group
    const int t = threadIdx.x;
    const int r = qt * 64 + t;

    __shared__ float Ks[64][64];
    __shared__ float Vs[64][64];

    const float* qrow = qb + (size_t)(b * Tt + r) * Dm + qoff;
    float qreg[64];
    #pragma unroll
    for (int i = 0; i < 16; i++) {
        float4 v4 = *(const float4*)(qrow + i * 4);
        qreg[i * 4 + 0] = v4.x * 0.125f;   // 1/sqrt(64)
        qreg[i * 4 + 1] = v4.y * 0.125f;
        qreg[i * 4 + 2] = v4.z * 0.125f;
        qreg[i * 4 + 3] = v4.w * 0.125f;
    }
    float m = -INFINITY, l = 0.0f;
    float o[64];
    #pragma unroll
    for (int i = 0; i < 64; i++) o[i] = 0.0f;

    const float* kbase = kb + (size_t)b * Tt * 256 + kvoff;
    const float* vbase = vb + (size_t)b * Tt * 256 + kvoff;

    for (int kt = 0; kt <= qt; kt++) {
        __syncthreads();
        const int lr = t >> 4, lc = t & 15;
        #pragma unroll
        for (int it = 0; it < 16; it++) {
            const int row = it * 4 + lr;
            const size_t goff = (size_t)(kt * 64 + row) * 256 + lc * 4;
            *(float4*)&Ks[row][lc * 4] = *(const float4*)(kbase + goff);
            *(float4*)&Vs[row][lc * 4] = *(const float4*)(vbase + goff);
        }
        __syncthreads();
        const bool diag = (kt == qt);
        for (int sub = 0; sub < 4; sub++) {
            float s[16];
            float tmax = -INFINITY;
            #pragma unroll
            for (int kk = 0; kk < 16; kk++) {
                const int krow = sub * 16 + kk;
                float acc = 0.0f;
                #pragma unroll
                for (int d4 = 0; d4 < 16; d4++) {
                    float4 kv = *(const float4*)&Ks[krow][d4 * 4];
                    acc = fmaf(qreg[d4 * 4 + 0], kv.x, acc);
                    acc = fmaf(qreg[d4 * 4 + 1], kv.y, acc);
                    acc = fmaf(qreg[d4 * 4 + 2], kv.z, acc);
                    acc = fmaf(qreg[d4 * 4 + 3], kv.w, acc);
                }
                if (diag && krow > t) acc = -INFINITY;  // causal mask
                s[kk] = acc;
                tmax = fmaxf(tmax, acc);
            }
            // online softmax update (tmax may be -inf if sub fully masked:
            // then newm == m (finite after first sub of tile 0), corr = 1)
            const float newm = fmaxf(m, tmax);
            const float corr = __expf(m - newm);  // m=-inf -> 0 first time
            l *= corr;
            #pragma unroll
            for (int i = 0; i < 64; i++) o[i] *= corr;
            #pragma unroll
            for (int kk = 0; kk < 16; kk++) {
                const float pp = __expf(s[kk] - newm);  // exp(-inf) = 0
                l += pp;
                const int krow = sub * 16 + kk;
                #pragma unroll
                for (int d4 = 0; d4 < 16; d4++) {
                    float4 vv = *(const float4*)&Vs[krow][d4 * 4];
                    o[d4 * 4 + 0] = fmaf(pp, vv.x, o[d4 * 4 + 0]);
                    o[d4 * 4 + 1] = fmaf(pp, vv.y, o[d4 * 4 + 1]);
                    o[d4 * 4 + 2] = fmaf(pp, vv.z, o[d4 * 4 + 2]);
                    o[d4 * 4 + 3] = fmaf(pp, vv.w, o[d4 * 4 + 3]);
                }
            }
            m = newm;
        }
    }
    const float inv = 1.0f / l;   // l > 0: every row attends at least to key 0
    float* orow = ob + (size_t)(b * Tt + r) * Dm + qoff;
    #pragma unroll
    for (int i = 0; i < 16; i++) {
        float4 v4;
        v4.x = o[i * 4 + 0] * inv;
        v4.y = o[i * 4 + 1] * inv;
        v4.z = o[i * 4 + 2] * inv;
        v4.w = o[i * 4 + 3] * inv;
        *(float4*)(orow + i * 4) = v4;
    }
}

// ---------------------------------------------------------------------------
// Launch: LN1 -> Q/K/V GEMMs -> attention -> Wo GEMM (+x residual, ->d_out)
//         -> LN2 -> FFN1 GEMM (+GELU) -> FFN2 GEMM (+residual, ->d_out)
// Workspace layout (fp32):
//   hbuf  [4096*1024]  h           (reused as attention output)
//   qbuf  [4096*1024]  q           (reused as h2)
//   kbuf  [4096* 256]  k
//   vbuf  [4096* 256]  v
//   f1    [4096*4096]  gelu(h2@w1+b1)
// Total ~109 MB.
// ---------------------------------------------------------------------------
extern "C" void kernel_launch(void* const* d_in, const int* in_sizes, int n_in,
                              void* d_out, int out_size, void* d_ws, size_t ws_size,
                              hipStream_t stream) {
    (void)in_sizes; (void)n_in; (void)out_size; (void)ws_size;
    const float* x   = (const float*)d_in[0];
    const float* g1  = (const float*)d_in[1];
    const float* bt1 = (const float*)d_in[2];
    const float* wq  = (const float*)d_in[3];
    const float* bq  = (const float*)d_in[4];
    const float* wk  = (const float*)d_in[5];
    const float* bk  = (const float*)d_in[6];
    const float* wv  = (const float*)d_in[7];
    const float* bv  = (const float*)d_in[8];
    const float* wo  = (const float*)d_in[9];
    const float* bo  = (const float*)d_in[10];
    const float* g2  = (const float*)d_in[11];
    const float* bt2 = (const float*)d_in[12];
    const float* w1  = (const float*)d_in[13];
    const float* b1  = (const float*)d_in[14];
    const float* w2  = (const float*)d_in[15];
    const float* b2  = (const float*)d_in[16];
    float* out = (float*)d_out;
    float* ws  = (float*)d_ws;

    const size_t S = (size_t)NROWS * Dm;            // 4096*1024
    float* hbuf = ws;                               // h, then attn out
    float* qbuf = ws + S;                           // q, then h2
    float* kbuf = ws + 2 * S;                       // k
    float* vbuf = ws + 2 * S + (size_t)NROWS * 256; // v
    float* f1   = ws + 2 * S + (size_t)2 * NROWS * 256; // 4096*4096

    // 1. h = LN1(x)
    ln_kernel<<<NROWS, 256, 0, stream>>>(x, g1, bt1, hbuf);
    // 2-4. q/k/v projections
    gemm_kernel<0><<<dim3(16, 64), 256, 0, stream>>>(hbuf, wq, bq, nullptr, qbuf, NROWS, 1024, 1024);
    gemm_kernel<0><<<dim3(4, 64), 256, 0, stream>>>(hbuf, wk, bk, nullptr, kbuf, NROWS, 256, 1024);
    gemm_kernel<0><<<dim3(4, 64), 256, 0, stream>>>(hbuf, wv, bv, nullptr, vbuf, NROWS, 256, 1024);
    // 5. causal GQA attention (hbuf now holds attention output)
    attn_kernel<<<NB * 16 * (Tt / 64), 64, 0, stream>>>(qbuf, kbuf, vbuf, hbuf);
    // 6. x2 = x + attn@wo + bo   -> d_out
    gemm_kernel<1><<<dim3(16, 64), 256, 0, stream>>>(hbuf, wo, bo, x, out, NROWS, 1024, 1024);
    // 7. h2 = LN2(x2)            -> qbuf
    ln_kernel<<<NROWS, 256, 0, stream>>>(out, g2, bt2, qbuf);
    // 8. f1 = gelu(h2@w1 + b1)
    gemm_kernel<2><<<dim3(64, 64), 256, 0, stream>>>(qbuf, w1, b1, nullptr, f1, NROWS, 4096, 1024);
    // 9. out = x2 + f1@w2 + b2   (in-place residual on d_out, per-element RAW by same thread)
    gemm_kernel<1><<<dim3(16, 64), 256, 0, stream>>>(f1, w2, b2, out, out, NROWS, 1024, 4096);
}

// Round 4
// 1512.786 us; speedup vs baseline: 2.3779x; 2.3779x over previous
//
#include <hip/hip_runtime.h>
#include <hip/hip_bf16.h>
#include <math.h>

constexpr int Dm = 1024;   // model dim
constexpr int Tt = 2048;   // seq len
constexpr int NB = 2;      // batch
constexpr int NROWS = NB * Tt;  // 4096

#define LN_EPS 1e-5f

typedef __attribute__((ext_vector_type(4))) float f32x4;
typedef __attribute__((ext_vector_type(8))) short short8;

// round-to-nearest-even fp32 -> bf16 (bit pattern)
__device__ __forceinline__ unsigned short f2bf(float f) {
    unsigned int u = __builtin_bit_cast(unsigned int, f);
    u += 0x7fffu + ((u >> 16) & 1u);
    return (unsigned short)(u >> 16);
}

__device__ __forceinline__ float gelu_exact(float v) {
    return 0.5f * v * (1.0f + erff(v * 0.70710678118654752f));
}

// async global->LDS, 16B per lane. lds base must be wave-uniform.
__device__ __forceinline__ void gload_lds16(const void* g, void* l) {
    __builtin_amdgcn_global_load_lds(
        (const __attribute__((address_space(1))) unsigned int*)g,
        (__attribute__((address_space(3))) unsigned int*)l, 16, 0, 0);
}

// ---------------------------------------------------------------------------
// LayerNorm: one block (256 threads) per row of 1024 floats -> bf16 out.
// ---------------------------------------------------------------------------
__global__ __launch_bounds__(256) void ln_kernel(const float* __restrict__ x,
        const float* __restrict__ gamma, const float* __restrict__ beta,
        unsigned short* __restrict__ out) {
    const int row = blockIdx.x;
    const int t = threadIdx.x;
    const float* xr = x + (size_t)row * Dm;
    float4 v = *(const float4*)(xr + t * 4);
    float s  = v.x + v.y + v.z + v.w;
    float s2 = v.x * v.x + v.y * v.y + v.z * v.z + v.w * v.w;
    #pragma unroll
    for (int off = 32; off > 0; off >>= 1) {
        s  += __shfl_down(s, off);
        s2 += __shfl_down(s2, off);
    }
    __shared__ float red[8];
    const int wid = t >> 6, lane = t & 63;
    if (lane == 0) { red[wid] = s; red[wid + 4] = s2; }
    __syncthreads();
    if (t == 0) {
        float a = red[0] + red[1] + red[2] + red[3];
        float c = red[4] + red[5] + red[6] + red[7];
        float mean = a * (1.0f / Dm);
        red[0] = mean;
        red[4] = c * (1.0f / Dm) - mean * mean;
    }
    __syncthreads();
    const float mean = red[0];
    const float rstd = rsqrtf(red[4] + LN_EPS);
    float4 gv = *(const float4*)(gamma + t * 4);
    float4 bv = *(const float4*)(beta + t * 4);
    ushort4 o;
    o.x = f2bf((v.x - mean) * rstd * gv.x + bv.x);
    o.y = f2bf((v.y - mean) * rstd * gv.y + bv.y);
    o.z = f2bf((v.z - mean) * rstd * gv.z + bv.z);
    o.w = f2bf((v.w - mean) * rstd * gv.w + bv.w);
    *(ushort4*)(out + (size_t)row * Dm + t * 4) = o;
}

// ---------------------------------------------------------------------------
// Weight transpose + fp32->bf16: W[K][N] -> Wt[N][K]. 64x64 tiles.
// ---------------------------------------------------------------------------
__global__ __launch_bounds__(256) void transpose_cvt(const float* __restrict__ W,
        unsigned short* __restrict__ Wt, int K, int N) {
    __shared__ float tile[64][65];
    const int k0 = blockIdx.x * 64, n0 = blockIdx.y * 64;
    const int t = threadIdx.x;
    const int r = t >> 2, c = t & 3;
    #pragma unroll
    for (int i = 0; i < 4; i++) {
        const int f4 = c + i * 4;
        *(float4*)&tile[r][f4 * 4] = *(const float4*)(W + (size_t)(k0 + r) * N + n0 + f4 * 4);
    }
    __syncthreads();
    #pragma unroll
    for (int i = 0; i < 4; i++) {
        const int kk = c * 16 + i * 4;
        ushort4 o;
        o.x = f2bf(tile[kk + 0][r]);
        o.y = f2bf(tile[kk + 1][r]);
        o.z = f2bf(tile[kk + 2][r]);
        o.w = f2bf(tile[kk + 3][r]);
        *(ushort4*)(Wt + (size_t)(n0 + r) * K + k0 + kk) = o;
    }
}

// ---------------------------------------------------------------------------
// bf16 MFMA GEMM: C[M,N] = A[M,K](bf16) @ Bt[N,K](bf16)^T + bias (+ epilogue)
// 128x128 tile, BK=32, 256 threads = 4 waves (2x2 of 64x64).
// EPI: 0 = bias (fp32 out), 1 = bias+residual (fp32 out), 2 = bias+GELU (bf16 out)
// ---------------------------------------------------------------------------
template<int EPI, typename OutT>
__global__ __launch_bounds__(256) void mgemm(
        const unsigned short* __restrict__ A,   // [M][K] bf16
        const unsigned short* __restrict__ Bt,  // [N][K] bf16
        const float* __restrict__ bias,         // [N]
        const float* __restrict__ res,          // [M][N] fp32 or null
        OutT* __restrict__ C,                   // [M][N]
        int M, int N, int K) {
    __shared__ __align__(16) unsigned short As[128 * 32];
    __shared__ __align__(16) unsigned short Bs[128 * 32];
    const int t = threadIdx.x;
    const int w = t >> 6, l = t & 63;
    const int wr = w >> 1, wc = w & 1;
    const int li = l & 15, lh = l >> 4;
    const int m0 = blockIdx.y * 128, n0 = blockIdx.x * 128;
    const int lrow = t >> 2, lseg = t & 3;
    const unsigned short* Ag = A  + (size_t)(m0 + lrow) * K + lseg * 8;
    const unsigned short* Bg = Bt + (size_t)(n0 + lrow) * K + lseg * 8;
    unsigned short* Asw = As + w * 512;   // wave chunk base (elems) = w*1024B
    unsigned short* Bsw = Bs + w * 512;
    f32x4 acc[4][4] = {};
    for (int k0 = 0; k0 < K; k0 += 32) {
        __syncthreads();   // previous compute done before LDS overwrite
        gload_lds16(Ag + k0, Asw);
        gload_lds16(Ag + (size_t)64 * K + k0, Asw + 2048);
        gload_lds16(Bg + k0, Bsw);
        gload_lds16(Bg + (size_t)64 * K + k0, Bsw + 2048);
        __syncthreads();   // drains vmcnt(0) -> staged data visible
        short8 af[4], bfr[4];
        #pragma unroll
        for (int m = 0; m < 4; m++)
            af[m] = *(const short8*)&As[(wr * 64 + m * 16 + li) * 32 + lh * 8];
        #pragma unroll
        for (int n = 0; n < 4; n++)
            bfr[n] = *(const short8*)&Bs[(wc * 64 + n * 16 + li) * 32 + lh * 8];
        #pragma unroll
        for (int m = 0; m < 4; m++)
            #pragma unroll
            for (int n = 0; n < 4; n++)
                acc[m][n] = __builtin_amdgcn_mfma_f32_16x16x32_bf16(af[m], bfr[n], acc[m][n], 0, 0, 0);
    }
    // epilogue: D[row][col], row = (l>>4)*4 + q, col = l&15 within each 16x16
    #pragma unroll
    for (int n = 0; n < 4; n++) {
        const int col = n0 + wc * 64 + n * 16 + li;
        const float bv = bias[col];
        #pragma unroll
        for (int m = 0; m < 4; m++) {
            const int rbase = m0 + wr * 64 + m * 16 + lh * 4;
            #pragma unroll
            for (int q = 0; q < 4; q++) {
                const size_t idx = (size_t)(rbase + q) * N + col;
                float v = acc[m][n][q] + bv;
                if (EPI == 1) v += res[idx];
                if (EPI == 2) v = gelu_exact(v);
                if constexpr (sizeof(OutT) == 2) C[idx] = (OutT)f2bf(v);
                else                             C[idx] = v;
            }
        }
    }
}

// ---------------------------------------------------------------------------
// Causal GQA flash attention, fp32, 4 lanes per q-row.
// Block = 256 threads (4 waves); wave w owns q-rows [qt*64+w*16, +16).
// Lane l: row li=l&15, dim-quarter qd=l>>4 (16 of 64 dims).
// Scores: quarter-dot + shfl_xor(16,32). K/V tile (64x64 fp32) in padded LDS.
// qt reversed so heaviest blocks launch first. Output bf16.
// ---------------------------------------------------------------------------
__global__ __launch_bounds__(256) void attn_kernel(
        const float* __restrict__ qb, const float* __restrict__ kb,
        const float* __restrict__ vb, unsigned short* __restrict__ ob) {
    const int blk = blockIdx.x;
    const int qt = 31 - (blk & 31);
    const int head = (blk >> 5) & 15;
    const int b = blk >> 9;
    const int g = head >> 2;
    const int t = threadIdx.x;
    const int w = t >> 6, l = t & 63;
    const int li = l & 15, qd = l >> 4;
    const int r = qt * 64 + w * 16 + li;

    __shared__ float Ks[64][68];
    __shared__ float Vs[64][68];

    float qreg[16];
    const float* qrow = qb + (size_t)(b * Tt + r) * Dm + head * 64 + qd * 16;
    #pragma unroll
    for (int j = 0; j < 4; j++) {
        float4 v4 = *(const float4*)(qrow + j * 4);
        qreg[j * 4 + 0] = v4.x * 0.125f;   // 1/sqrt(64)
        qreg[j * 4 + 1] = v4.y * 0.125f;
        qreg[j * 4 + 2] = v4.z * 0.125f;
        qreg[j * 4 + 3] = v4.w * 0.125f;
    }
    float m = -INFINITY, lsum = 0.0f;
    float o[16] = {};

    const int srow = t >> 2, sc = t & 3;
    const float* kbase = kb + (size_t)b * Tt * 256 + g * 64;
    const float* vbase = vb + (size_t)b * Tt * 256 + g * 64;

    for (int kt = 0; kt <= qt; kt++) {
        __syncthreads();
        const float* kp = kbase + (size_t)(kt * 64 + srow) * 256;
        const float* vp = vbase + (size_t)(kt * 64 + srow) * 256;
        #pragma unroll
        for (int i = 0; i < 4; i++) {
            const int c = (sc + i * 4) * 4;
            *(float4*)&Ks[srow][c] = *(const float4*)(kp + c);
            *(float4*)&Vs[srow][c] = *(const float4*)(vp + c);
        }
        __syncthreads();
        const bool diag = (kt == qt);
        #pragma unroll 1
        for (int sub = 0; sub < 4; sub++) {
            if (diag && sub * 16 > w * 16 + 15) break;  // fully-masked subtile
            float s[16];
            float tmax = -INFINITY;
            #pragma unroll
            for (int kk = 0; kk < 16; kk++) {
                const int key = sub * 16 + kk;
                float acc = 0.0f;
                #pragma unroll
                for (int j = 0; j < 4; j++) {
                    float4 kv = *(const float4*)&Ks[key][qd * 16 + j * 4];
                    acc = fmaf(qreg[j * 4 + 0], kv.x, acc);
                    acc = fmaf(qreg[j * 4 + 1], kv.y, acc);
                    acc = fmaf(qreg[j * 4 + 2], kv.z, acc);
                    acc = fmaf(qreg[j * 4 + 3], kv.w, acc);
                }
                acc += __shfl_xor(acc, 16);
                acc += __shfl_xor(acc, 32);   // full 64-dim dot in all lanes
                if (diag && key > w * 16 + li) acc = -INFINITY;  // causal mask
                s[kk] = acc;
                tmax = fmaxf(tmax, acc);
            }
            const float newm = fmaxf(m, tmax);
            const float corr = __expf(m - newm);   // m=-inf first time -> 0
            lsum *= corr;
            #pragma unroll
            for (int i = 0; i < 16; i++) o[i] *= corr;
            #pragma unroll
            for (int kk = 0; kk < 16; kk++) {
                const int key = sub * 16 + kk;
                const float p = __expf(s[kk] - newm);   // exp(-inf) = 0
                lsum += p;
                #pragma unroll
                for (int j = 0; j < 4; j++) {
                    float4 vv = *(const float4*)&Vs[key][qd * 16 + j * 4];
                    o[j * 4 + 0] = fmaf(p, vv.x, o[j * 4 + 0]);
                    o[j * 4 + 1] = fmaf(p, vv.y, o[j * 4 + 1]);
                    o[j * 4 + 2] = fmaf(p, vv.z, o[j * 4 + 2]);
                    o[j * 4 + 3] = fmaf(p, vv.w, o[j * 4 + 3]);
                }
            }
            m = newm;
        }
    }
    const float inv = 1.0f / lsum;
    unsigned short* orow = ob + (size_t)(b * Tt + r) * Dm + head * 64 + qd * 16;
    #pragma unroll
    for (int j = 0; j < 4; j++) {
        ushort4 o4;
        o4.x = f2bf(o[j * 4 + 0] * inv);
        o4.y = f2bf(o[j * 4 + 1] * inv);
        o4.z = f2bf(o[j * 4 + 2] * inv);
        o4.w = f2bf(o[j * 4 + 3] * inv);
        *(ushort4*)(orow + j * 4) = o4;
    }
}

// ---------------------------------------------------------------------------
extern "C" void kernel_launch(void* const* d_in, const int* in_sizes, int n_in,
                              void* d_out, int out_size, void* d_ws, size_t ws_size,
                              hipStream_t stream) {
    (void)in_sizes; (void)n_in; (void)out_size; (void)ws_size;
    const float* x   = (const float*)d_in[0];
    const float* g1  = (const float*)d_in[1];
    const float* bt1 = (const float*)d_in[2];
    const float* wq  = (const float*)d_in[3];
    const float* bq  = (const float*)d_in[4];
    const float* wk  = (const float*)d_in[5];
    const float* bk  = (const float*)d_in[6];
    const float* wv  = (const float*)d_in[7];
    const float* bv  = (const float*)d_in[8];
    const float* wo  = (const float*)d_in[9];
    const float* bo  = (const float*)d_in[10];
    const float* g2  = (const float*)d_in[11];
    const float* bt2 = (const float*)d_in[12];
    const float* w1  = (const float*)d_in[13];
    const float* b1  = (const float*)d_in[14];
    const float* w2  = (const float*)d_in[15];
    const float* b2  = (const float*)d_in[16];
    float* out = (float*)d_out;

    // workspace layout (bytes)
    char* p = (char*)d_ws;
    unsigned short* h_bf  = (unsigned short*)p; p += (size_t)NROWS * Dm * 2;     // 8 MB
    unsigned short* h2_bf = (unsigned short*)p; p += (size_t)NROWS * Dm * 2;     // 8 MB
    unsigned short* at_bf = (unsigned short*)p; p += (size_t)NROWS * Dm * 2;     // 8 MB
    unsigned short* f1_bf = (unsigned short*)p; p += (size_t)NROWS * 4096 * 2;   // 32 MB
    float* q_f = (float*)p; p += (size_t)NROWS * 1024 * 4;                       // 16 MB
    float* k_f = (float*)p; p += (size_t)NROWS * 256 * 4;                        // 4 MB
    float* v_f = (float*)p; p += (size_t)NROWS * 256 * 4;                        // 4 MB
    unsigned short* wqT = (unsigned short*)p; p += (size_t)1024 * 1024 * 2;
    unsigned short* wkT = (unsigned short*)p; p += (size_t)256 * 1024 * 2;
    unsigned short* wvT = (unsigned short*)p; p += (size_t)256 * 1024 * 2;
    unsigned short* woT = (unsigned short*)p; p += (size_t)1024 * 1024 * 2;
    unsigned short* w1T = (unsigned short*)p; p += (size_t)4096 * 1024 * 2;
    unsigned short* w2T = (unsigned short*)p; p += (size_t)1024 * 4096 * 2;

    // 0. weight transpose + bf16 convert: W[K][N] -> Wt[N][K]
    transpose_cvt<<<dim3(16, 16), 256, 0, stream>>>(wq, wqT, 1024, 1024);
    transpose_cvt<<<dim3(16, 4),  256, 0, stream>>>(wk, wkT, 1024, 256);
    transpose_cvt<<<dim3(16, 4),  256, 0, stream>>>(wv, wvT, 1024, 256);
    transpose_cvt<<<dim3(16, 16), 256, 0, stream>>>(wo, woT, 1024, 1024);
    transpose_cvt<<<dim3(16, 64), 256, 0, stream>>>(w1, w1T, 1024, 4096);
    transpose_cvt<<<dim3(64, 16), 256, 0, stream>>>(w2, w2T, 4096, 1024);

    // 1. h = LN1(x) -> bf16
    ln_kernel<<<NROWS, 256, 0, stream>>>(x, g1, bt1, h_bf);
    // 2-4. q/k/v projections (fp32 out for attention)
    mgemm<0, float><<<dim3(8, 32), 256, 0, stream>>>(h_bf, wqT, bq, nullptr, q_f, NROWS, 1024, 1024);
    mgemm<0, float><<<dim3(2, 32), 256, 0, stream>>>(h_bf, wkT, bk, nullptr, k_f, NROWS, 256, 1024);
    mgemm<0, float><<<dim3(2, 32), 256, 0, stream>>>(h_bf, wvT, bv, nullptr, v_f, NROWS, 256, 1024);
    // 5. attention -> bf16
    attn_kernel<<<NB * 16 * (Tt / 64), 256, 0, stream>>>(q_f, k_f, v_f, at_bf);
    // 6. x2 = x + attn@wo + bo -> d_out (fp32)
    mgemm<1, float><<<dim3(8, 32), 256, 0, stream>>>(at_bf, woT, bo, x, out, NROWS, 1024, 1024);
    // 7. h2 = LN2(x2) -> bf16
    ln_kernel<<<NROWS, 256, 0, stream>>>(out, g2, bt2, h2_bf);
    // 8. f1 = gelu(h2@w1 + b1) -> bf16
    mgemm<2, unsigned short><<<dim3(32, 32), 256, 0, stream>>>(h2_bf, w1T, b1, nullptr, f1_bf, NROWS, 4096, 1024);
    // 9. out = x2 + f1@w2 + b2 (in-place residual, per-element same-thread RAW)
    mgemm<1, float><<<dim3(8, 32), 256, 0, stream>>>(f1_bf, w2T, b2, out, out, NROWS, 1024, 4096);
}

// Round 6
// 571.967 us; speedup vs baseline: 6.2892x; 2.6449x over previous
//
#include <hip/hip_runtime.h>
#include <hip/hip_bf16.h>
#include <math.h>

constexpr int Dm = 1024;   // model dim
constexpr int Tt = 2048;   // seq len
constexpr int NB = 2;      // batch
constexpr int NROWS = NB * Tt;  // 4096

#define LN_EPS 1e-5f

typedef __attribute__((ext_vector_type(4))) float f32x4;
typedef __attribute__((ext_vector_type(8))) short short8;

// round-to-nearest-even fp32 -> bf16 (bit pattern)
__device__ __forceinline__ unsigned short f2bf(float f) {
    unsigned int u = __builtin_bit_cast(unsigned int, f);
    u += 0x7fffu + ((u >> 16) & 1u);
    return (unsigned short)(u >> 16);
}
__device__ __forceinline__ float bf2f(unsigned short u) {
    unsigned int v = (unsigned int)u << 16;
    return __builtin_bit_cast(float, v);
}

__device__ __forceinline__ float gelu_exact(float v) {
    return 0.5f * v * (1.0f + erff(v * 0.70710678118654752f));
}

// async global->LDS, 16B per lane. lds base must be wave-uniform.
__device__ __forceinline__ void gload_lds16(const void* g, void* l) {
    __builtin_amdgcn_global_load_lds(
        (const __attribute__((address_space(1))) unsigned int*)g,
        (__attribute__((address_space(3))) unsigned int*)l, 16, 0, 0);
}

// ---------------------------------------------------------------------------
// LayerNorm: one block (256 threads) per row of 1024 floats -> bf16 out.
// ---------------------------------------------------------------------------
__global__ __launch_bounds__(256) void ln_kernel(const float* __restrict__ x,
        const float* __restrict__ gamma, const float* __restrict__ beta,
        unsigned short* __restrict__ out) {
    const int row = blockIdx.x;
    const int t = threadIdx.x;
    const float* xr = x + (size_t)row * Dm;
    float4 v = *(const float4*)(xr + t * 4);
    float s  = v.x + v.y + v.z + v.w;
    float s2 = v.x * v.x + v.y * v.y + v.z * v.z + v.w * v.w;
    #pragma unroll
    for (int off = 32; off > 0; off >>= 1) {
        s  += __shfl_down(s, off);
        s2 += __shfl_down(s2, off);
    }
    __shared__ float red[8];
    const int wid = t >> 6, lane = t & 63;
    if (lane == 0) { red[wid] = s; red[wid + 4] = s2; }
    __syncthreads();
    if (t == 0) {
        float a = red[0] + red[1] + red[2] + red[3];
        float c = red[4] + red[5] + red[6] + red[7];
        float mean = a * (1.0f / Dm);
        red[0] = mean;
        red[4] = c * (1.0f / Dm) - mean * mean;
    }
    __syncthreads();
    const float mean = red[0];
    const float rstd = rsqrtf(red[4] + LN_EPS);
    float4 gv = *(const float4*)(gamma + t * 4);
    float4 bv = *(const float4*)(beta + t * 4);
    ushort4 o;
    o.x = f2bf((v.x - mean) * rstd * gv.x + bv.x);
    o.y = f2bf((v.y - mean) * rstd * gv.y + bv.y);
    o.z = f2bf((v.z - mean) * rstd * gv.z + bv.z);
    o.w = f2bf((v.w - mean) * rstd * gv.w + bv.w);
    *(ushort4*)(out + (size_t)row * Dm + t * 4) = o;
}

// ---------------------------------------------------------------------------
// Weight transpose + fp32->bf16: W[K][N] -> Wt[N][K]. 64x64 tiles.
// ---------------------------------------------------------------------------
__global__ __launch_bounds__(256) void transpose_cvt(const float* __restrict__ W,
        unsigned short* __restrict__ Wt, int K, int N) {
    __shared__ float tile[64][65];
    const int k0 = blockIdx.x * 64, n0 = blockIdx.y * 64;
    const int t = threadIdx.x;
    const int r = t >> 2, c = t & 3;
    #pragma unroll
    for (int i = 0; i < 4; i++) {
        const int f4 = c + i * 4;
        *(float4*)&tile[r][f4 * 4] = *(const float4*)(W + (size_t)(k0 + r) * N + n0 + f4 * 4);
    }
    __syncthreads();
    #pragma unroll
    for (int i = 0; i < 4; i++) {
        const int kk = c * 16 + i * 4;
        ushort4 o;
        o.x = f2bf(tile[kk + 0][r]);
        o.y = f2bf(tile[kk + 1][r]);
        o.z = f2bf(tile[kk + 2][r]);
        o.w = f2bf(tile[kk + 3][r]);
        *(ushort4*)(Wt + (size_t)(n0 + r) * K + k0 + kk) = o;
    }
}

// ---------------------------------------------------------------------------
// bf16 MFMA GEMM: C[M,N] = A[M,K](bf16) @ Bt[N,K](bf16)^T + bias (+ epilogue)
// 128x128 tile, BK=32, 256 threads = 4 waves (2x2 of 64x64).
// EPI: 0 = bias, 1 = bias+residual (fp32 res), 2 = bias+GELU
// ---------------------------------------------------------------------------
template<int EPI, typename OutT>
__global__ __launch_bounds__(256) void mgemm(
        const unsigned short* __restrict__ A,   // [M][K] bf16
        const unsigned short* __restrict__ Bt,  // [N][K] bf16
        const float* __restrict__ bias,         // [N]
        const float* __restrict__ res,          // [M][N] fp32 or null
        OutT* __restrict__ C,                   // [M][N]
        int M, int N, int K) {
    __shared__ __align__(16) unsigned short As[128 * 32];
    __shared__ __align__(16) unsigned short Bs[128 * 32];
    const int t = threadIdx.x;
    const int w = t >> 6, l = t & 63;
    const int wr = w >> 1, wc = w & 1;
    const int li = l & 15, lh = l >> 4;
    const int m0 = blockIdx.y * 128, n0 = blockIdx.x * 128;
    const int lrow = t >> 2, lseg = t & 3;
    const unsigned short* Ag = A  + (size_t)(m0 + lrow) * K + lseg * 8;
    const unsigned short* Bg = Bt + (size_t)(n0 + lrow) * K + lseg * 8;
    unsigned short* Asw = As + w * 512;   // wave chunk base (elems) = w*1024B
    unsigned short* Bsw = Bs + w * 512;
    f32x4 acc[4][4] = {};
    for (int k0 = 0; k0 < K; k0 += 32) {
        __syncthreads();   // previous compute done before LDS overwrite
        gload_lds16(Ag + k0, Asw);
        gload_lds16(Ag + (size_t)64 * K + k0, Asw + 2048);
        gload_lds16(Bg + k0, Bsw);
        gload_lds16(Bg + (size_t)64 * K + k0, Bsw + 2048);
        __syncthreads();   // drains vmcnt(0) -> staged data visible
        short8 af[4], bfr[4];
        #pragma unroll
        for (int m = 0; m < 4; m++)
            af[m] = *(const short8*)&As[(wr * 64 + m * 16 + li) * 32 + lh * 8];
        #pragma unroll
        for (int n = 0; n < 4; n++)
            bfr[n] = *(const short8*)&Bs[(wc * 64 + n * 16 + li) * 32 + lh * 8];
        #pragma unroll
        for (int m = 0; m < 4; m++)
            #pragma unroll
            for (int n = 0; n < 4; n++)
                acc[m][n] = __builtin_amdgcn_mfma_f32_16x16x32_bf16(af[m], bfr[n], acc[m][n], 0, 0, 0);
    }
    // epilogue: D[row][col], row = (l>>4)*4 + q, col = l&15 within each 16x16
    #pragma unroll
    for (int n = 0; n < 4; n++) {
        const int col = n0 + wc * 64 + n * 16 + li;
        const float bv = bias[col];
        #pragma unroll
        for (int m = 0; m < 4; m++) {
            const int rbase = m0 + wr * 64 + m * 16 + lh * 4;
            #pragma unroll
            for (int q = 0; q < 4; q++) {
                const size_t idx = (size_t)(rbase + q) * N + col;
                float v = acc[m][n][q] + bv;
                if (EPI == 1) v += res[idx];
                if (EPI == 2) v = gelu_exact(v);
                if constexpr (sizeof(OutT) == 2) C[idx] = (OutT)f2bf(v);
                else                             C[idx] = v;
            }
        }
    }
}

// ---------------------------------------------------------------------------
// Causal GQA flash attention, bf16 MFMA.
// Grid: NB*16*(Tt/64) blocks; block = 256 threads = 4 waves.
// Block handles (b, head, qt): 64 q-rows; wave w owns rows [w*16, w*16+16).
// Per 64-key KV tile:
//   stage K[key][dim] and Vt[dim][key] (bf16) in XOR-swizzled LDS
//   QK^T: 4 key-tiles x 2 k-steps of mfma_16x16x32 (A=Q regs, B=K rows)
//   online softmax (rows live in C-layout: row=lh*4+r, col=li=key)
//   P (bf16) -> wave-private swizzled LDS -> A-frags for PV
//   PV: 4 dim-tiles x 2 k-steps (B=Vt rows)
// Fragment conventions identical to mgemm (verified r1):
//   A-frag: lane row=l&15, k-slice=(l>>4)*8;  B-frag: lane col=l&15
//   C/D: row=(l>>4)*4+reg, col=l&15
// Swizzle: elem_in_row ^= (row&7)<<3  (16B-block granular, G4)
// ---------------------------------------------------------------------------
__global__ __launch_bounds__(256) void attn_mfma(
        const unsigned short* __restrict__ qb,  // [4096][1024] bf16
        const unsigned short* __restrict__ kb,  // [4096][256]  bf16
        const unsigned short* __restrict__ vb,  // [4096][256]  bf16
        unsigned short* __restrict__ ob) {      // [4096][1024] bf16
    const int blk = blockIdx.x;
    const int qt = 31 - (blk & 31);          // heaviest first
    const int head = (blk >> 5) & 15;
    const int b = blk >> 9;
    const int g = head >> 2;
    const int t = threadIdx.x;
    const int w = t >> 6, l = t & 63;
    const int li = l & 15, lh = l >> 4;
    const int sw = (li & 7) << 3;            // read-side swizzle (row&7 == li&7)

    __shared__ __align__(16) unsigned short Ks[64 * 64];   // [key][dim] swz
    __shared__ __align__(16) unsigned short Vt[64 * 64];   // [dim][key] swz
    __shared__ __align__(16) unsigned short Pl[4][16 * 64];// per-wave [q][key] swz

    unsigned short* Pw = Pl[w];

    // Q fragments in registers, prescaled by 1/8 (exact in bf16: pow2)
    short8 aq[2];
    {
        const unsigned short* qrow =
            qb + (size_t)(b * Tt + qt * 64 + w * 16 + li) * Dm + head * 64;
        #pragma unroll
        for (int s = 0; s < 2; s++) {
            uint4 raw = *(const uint4*)(qrow + s * 32 + lh * 8);
            unsigned short* u = (unsigned short*)&raw;
            #pragma unroll
            for (int j = 0; j < 8; j++) u[j] = f2bf(bf2f(u[j]) * 0.125f);
            aq[s] = *(const short8*)&raw;
        }
    }

    float mrow[4], lrow[4];
    f32x4 acc[4] = {};
    #pragma unroll
    for (int r = 0; r < 4; r++) { mrow[r] = -INFINITY; lrow[r] = 0.0f; }

    const unsigned short* kgb = kb + (size_t)(b * Tt) * 256 + g * 64;
    const unsigned short* vgb = vb + (size_t)(b * Tt) * 256 + g * 64;
    const int skey = t >> 3, sseg = t & 7;   // staging: 32 keys x 8 segs / round

    for (int kt = 0; kt <= qt; kt++) {
        __syncthreads();   // all waves done reading previous K/V tile
        // ---- stage K and V^T (2 rounds of 32 key-rows) ----
        #pragma unroll
        for (int i = 0; i < 2; i++) {
            const int key = i * 32 + skey;
            const size_t gro = (size_t)(kt * 64 + key) * 256 + sseg * 8;
            uint4 k4 = *(const uint4*)(kgb + gro);
            *(uint4*)&Ks[key * 64 + ((sseg * 8) ^ ((key & 7) << 3))] = k4;
            uint4 v4 = *(const uint4*)(vgb + gro);
            const unsigned short* vp = (const unsigned short*)&v4;
            #pragma unroll
            for (int j = 0; j < 8; j++) {
                const int dim = sseg * 8 + j;       // dim&7 == j
                Vt[dim * 64 + (key ^ (j << 3))] = vp[j];
            }
        }
        __syncthreads();

        const bool diagt = (kt == qt);
        // ---- QK^T ----
        f32x4 s4[4];
        #pragma unroll
        for (int tile = 0; tile < 4; tile++)
            s4[tile] = (f32x4){-INFINITY, -INFINITY, -INFINITY, -INFINITY};
        #pragma unroll
        for (int tile = 0; tile < 4; tile++) {
            if (diagt && tile > w) continue;     // fully masked for this wave
            f32x4 z = {};
            #pragma unroll
            for (int s = 0; s < 2; s++) {
                short8 bk = *(const short8*)
                    &Ks[(tile * 16 + li) * 64 + ((s * 32 + lh * 8) ^ sw)];
                z = __builtin_amdgcn_mfma_f32_16x16x32_bf16(aq[s], bk, z, 0, 0, 0);
            }
            if (diagt && tile == w) {            // mask key>q on the diagonal
                #pragma unroll
                for (int r = 0; r < 4; r++)
                    if (li > lh * 4 + r) z[r] = -INFINITY;
            }
            s4[tile] = z;
        }
        // ---- online softmax (rows = lh*4+r, shared by the 16 li-lanes) ----
        float mx[4];
        #pragma unroll
        for (int r = 0; r < 4; r++) {
            float v = s4[0][r];
            v = fmaxf(v, s4[1][r]); v = fmaxf(v, s4[2][r]); v = fmaxf(v, s4[3][r]);
            mx[r] = v;
        }
        #pragma unroll
        for (int off = 1; off < 16; off <<= 1)
            #pragma unroll
            for (int r = 0; r < 4; r++)
                mx[r] = fmaxf(mx[r], __shfl_xor(mx[r], off));
        float corr[4];
        #pragma unroll
        for (int r = 0; r < 4; r++) {
            const float nm = fmaxf(mrow[r], mx[r]);   // finite after tile 0
            corr[r] = __expf(mrow[r] - nm);           // -inf -> 0 first time
            mrow[r] = nm;
        }
        float p[4][4], rs[4] = {};
        #pragma unroll
        for (int tile = 0; tile < 4; tile++)
            #pragma unroll
            for (int r = 0; r < 4; r++) {
                const float pv = __expf(s4[tile][r] - mrow[r]);  // exp(-inf)=0
                p[tile][r] = pv;
                rs[r] += pv;
            }
        #pragma unroll
        for (int off = 1; off < 16; off <<= 1)
            #pragma unroll
            for (int r = 0; r < 4; r++)
                rs[r] += __shfl_xor(rs[r], off);
        #pragma unroll
        for (int r = 0; r < 4; r++)
            lrow[r] = lrow[r] * corr[r] + rs[r];
        #pragma unroll
        for (int n = 0; n < 4; n++)
            #pragma unroll
            for (int r = 0; r < 4; r++)
                acc[n][r] *= corr[r];
        // ---- P -> LDS (wave-private; zero for masked tiles) ----
        #pragma unroll
        for (int tile = 0; tile < 4; tile++)
            #pragma unroll
            for (int r = 0; r < 4; r++) {
                const int q = lh * 4 + r;
                Pw[q * 64 + ((tile * 16 + li) ^ ((q & 7) << 3))] = f2bf(p[tile][r]);
            }
        // ---- PV (compiler inserts lgkmcnt for P write->read dependency) ----
        #pragma unroll
        for (int s = 0; s < 2; s++) {
            short8 pa = *(const short8*)&Pw[li * 64 + ((s * 32 + lh * 8) ^ sw)];
            #pragma unroll
            for (int n = 0; n < 4; n++) {
                short8 bv = *(const short8*)
                    &Vt[(n * 16 + li) * 64 + ((s * 32 + lh * 8) ^ sw)];
                acc[n] = __builtin_amdgcn_mfma_f32_16x16x32_bf16(pa, bv, acc[n], 0, 0, 0);
            }
        }
    }
    // ---- epilogue: out[q][dim] = acc/l ----
    float inv[4];
    #pragma unroll
    for (int r = 0; r < 4; r++) inv[r] = 1.0f / lrow[r];
    unsigned short* orow =
        ob + (size_t)(b * Tt + qt * 64 + w * 16) * Dm + head * 64;
    #pragma unroll
    for (int n = 0; n < 4; n++)
        #pragma unroll
        for (int r = 0; r < 4; r++)
            orow[(size_t)(lh * 4 + r) * Dm + n * 16 + li] = f2bf(acc[n][r] * inv[r]);
}

// ---------------------------------------------------------------------------
extern "C" void kernel_launch(void* const* d_in, const int* in_sizes, int n_in,
                              void* d_out, int out_size, void* d_ws, size_t ws_size,
                              hipStream_t stream) {
    (void)in_sizes; (void)n_in; (void)out_size; (void)ws_size;
    const float* x   = (const float*)d_in[0];
    const float* g1  = (const float*)d_in[1];
    const float* bt1 = (const float*)d_in[2];
    const float* wq  = (const float*)d_in[3];
    const float* bq  = (const float*)d_in[4];
    const float* wk  = (const float*)d_in[5];
    const float* bk  = (const float*)d_in[6];
    const float* wv  = (const float*)d_in[7];
    const float* bv  = (const float*)d_in[8];
    const float* wo  = (const float*)d_in[9];
    const float* bo  = (const float*)d_in[10];
    const float* g2  = (const float*)d_in[11];
    const float* bt2 = (const float*)d_in[12];
    const float* w1  = (const float*)d_in[13];
    const float* b1  = (const float*)d_in[14];
    const float* w2  = (const float*)d_in[15];
    const float* b2  = (const float*)d_in[16];
    float* out = (float*)d_out;

    // workspace layout (bytes)
    char* p = (char*)d_ws;
    unsigned short* h_bf  = (unsigned short*)p; p += (size_t)NROWS * Dm * 2;     // 8 MB
    unsigned short* h2_bf = (unsigned short*)p; p += (size_t)NROWS * Dm * 2;     // 8 MB
    unsigned short* at_bf = (unsigned short*)p; p += (size_t)NROWS * Dm * 2;     // 8 MB
    unsigned short* f1_bf = (unsigned short*)p; p += (size_t)NROWS * 4096 * 2;   // 32 MB
    unsigned short* q_bf  = (unsigned short*)p; p += (size_t)NROWS * 1024 * 2;   // 8 MB
    unsigned short* k_bf  = (unsigned short*)p; p += (size_t)NROWS * 256 * 2;    // 2 MB
    unsigned short* v_bf  = (unsigned short*)p; p += (size_t)NROWS * 256 * 2;    // 2 MB
    unsigned short* wqT = (unsigned short*)p; p += (size_t)1024 * 1024 * 2;
    unsigned short* wkT = (unsigned short*)p; p += (size_t)256 * 1024 * 2;
    unsigned short* wvT = (unsigned short*)p; p += (size_t)256 * 1024 * 2;
    unsigned short* woT = (unsigned short*)p; p += (size_t)1024 * 1024 * 2;
    unsigned short* w1T = (unsigned short*)p; p += (size_t)4096 * 1024 * 2;
    unsigned short* w2T = (unsigned short*)p; p += (size_t)1024 * 4096 * 2;

    // 0. weight transpose + bf16 convert: W[K][N] -> Wt[N][K]
    transpose_cvt<<<dim3(16, 16), 256, 0, stream>>>(wq, wqT, 1024, 1024);
    transpose_cvt<<<dim3(16, 4),  256, 0, stream>>>(wk, wkT, 1024, 256);
    transpose_cvt<<<dim3(16, 4),  256, 0, stream>>>(wv, wvT, 1024, 256);
    transpose_cvt<<<dim3(16, 16), 256, 0, stream>>>(wo, woT, 1024, 1024);
    transpose_cvt<<<dim3(16, 64), 256, 0, stream>>>(w1, w1T, 1024, 4096);
    transpose_cvt<<<dim3(64, 16), 256, 0, stream>>>(w2, w2T, 4096, 1024);

    // 1. h = LN1(x) -> bf16
    ln_kernel<<<NROWS, 256, 0, stream>>>(x, g1, bt1, h_bf);
    // 2-4. q/k/v projections -> bf16 (MFMA attention inputs)
    mgemm<0, unsigned short><<<dim3(8, 32), 256, 0, stream>>>(h_bf, wqT, bq, nullptr, q_bf, NROWS, 1024, 1024);
    mgemm<0, unsigned short><<<dim3(2, 32), 256, 0, stream>>>(h_bf, wkT, bk, nullptr, k_bf, NROWS, 256, 1024);
    mgemm<0, unsigned short><<<dim3(2, 32), 256, 0, stream>>>(h_bf, wvT, bv, nullptr, v_bf, NROWS, 256, 1024);
    // 5. attention (bf16 MFMA) -> bf16
    attn_mfma<<<NB * 16 * (Tt / 64), 256, 0, stream>>>(q_bf, k_bf, v_bf, at_bf);
    // 6. x2 = x + attn@wo + bo -> d_out (fp32)
    mgemm<1, float><<<dim3(8, 32), 256, 0, stream>>>(at_bf, woT, bo, x, out, NROWS, 1024, 1024);
    // 7. h2 = LN2(x2) -> bf16
    ln_kernel<<<NROWS, 256, 0, stream>>>(out, g2, bt2, h2_bf);
    // 8. f1 = gelu(h2@w1 + b1) -> bf16
    mgemm<2, unsigned short><<<dim3(32, 32), 256, 0, stream>>>(h2_bf, w1T, b1, nullptr, f1_bf, NROWS, 4096, 1024);
    // 9. out = x2 + f1@w2 + b2 (in-place residual, per-element same-thread RAW)
    mgemm<1, float><<<dim3(8, 32), 256, 0, stream>>>(f1_bf, w2T, b2, out, out, NROWS, 1024, 4096);
}

// Round 10
// 492.888 us; speedup vs baseline: 7.2982x; 1.1604x over previous
//
#include <hip/hip_runtime.h>
#include <hip/hip_bf16.h>
#include <math.h>

constexpr int Dm = 1024;   // model dim
constexpr int Tt = 2048;   // seq len
constexpr int NB = 2;      // batch
constexpr int NROWS = NB * Tt;  // 4096

#define LN_EPS 1e-5f

typedef __attribute__((ext_vector_type(4))) float f32x4;
typedef __attribute__((ext_vector_type(8))) short short8;

// round-to-nearest-even fp32 -> bf16 (bit pattern)
__device__ __forceinline__ unsigned short f2bf(float f) {
    unsigned int u = __builtin_bit_cast(unsigned int, f);
    u += 0x7fffu + ((u >> 16) & 1u);
    return (unsigned short)(u >> 16);
}
__device__ __forceinline__ float bf2f(unsigned short u) {
    unsigned int v = (unsigned int)u << 16;
    return __builtin_bit_cast(float, v);
}

__device__ __forceinline__ float gelu_exact(float v) {
    return 0.5f * v * (1.0f + erff(v * 0.70710678118654752f));
}

// async global->LDS, 16B per lane. lds base must be wave-uniform; global src per-lane.
__device__ __forceinline__ void gload_lds16(const void* g, void* l) {
    __builtin_amdgcn_global_load_lds(
        (const __attribute__((address_space(1))) unsigned int*)g,
        (__attribute__((address_space(3))) unsigned int*)l, 16, 0, 0);
}

// ---------------------------------------------------------------------------
// LayerNorm: one block (256 threads) per row of 1024 floats -> bf16 out.
// ---------------------------------------------------------------------------
__global__ __launch_bounds__(256) void ln_kernel(const float* __restrict__ x,
        const float* __restrict__ gamma, const float* __restrict__ beta,
        unsigned short* __restrict__ out) {
    const int row = blockIdx.x;
    const int t = threadIdx.x;
    const float* xr = x + (size_t)row * Dm;
    float4 v = *(const float4*)(xr + t * 4);
    float s  = v.x + v.y + v.z + v.w;
    float s2 = v.x * v.x + v.y * v.y + v.z * v.z + v.w * v.w;
    #pragma unroll
    for (int off = 32; off > 0; off >>= 1) {
        s  += __shfl_down(s, off);
        s2 += __shfl_down(s2, off);
    }
    __shared__ float red[8];
    const int wid = t >> 6, lane = t & 63;
    if (lane == 0) { red[wid] = s; red[wid + 4] = s2; }
    __syncthreads();
    if (t == 0) {
        float a = red[0] + red[1] + red[2] + red[3];
        float c = red[4] + red[5] + red[6] + red[7];
        float mean = a * (1.0f / Dm);
        red[0] = mean;
        red[4] = c * (1.0f / Dm) - mean * mean;
    }
    __syncthreads();
    const float mean = red[0];
    const float rstd = rsqrtf(red[4] + LN_EPS);
    float4 gv = *(const float4*)(gamma + t * 4);
    float4 bv = *(const float4*)(beta + t * 4);
    ushort4 o;
    o.x = f2bf((v.x - mean) * rstd * gv.x + bv.x);
    o.y = f2bf((v.y - mean) * rstd * gv.y + bv.y);
    o.z = f2bf((v.z - mean) * rstd * gv.z + bv.z);
    o.w = f2bf((v.w - mean) * rstd * gv.w + bv.w);
    *(ushort4*)(out + (size_t)row * Dm + t * 4) = o;
}

// ---------------------------------------------------------------------------
// Weight transpose + fp32->bf16: W[K][N] -> Wt[N][K]. 64x64 tiles.
// ---------------------------------------------------------------------------
__global__ __launch_bounds__(256) void transpose_cvt(const float* __restrict__ W,
        unsigned short* __restrict__ Wt, int K, int N) {
    __shared__ float tile[64][65];
    const int k0 = blockIdx.x * 64, n0 = blockIdx.y * 64;
    const int t = threadIdx.x;
    const int r = t >> 2, c = t & 3;
    #pragma unroll
    for (int i = 0; i < 4; i++) {
        const int f4 = c + i * 4;
        *(float4*)&tile[r][f4 * 4] = *(const float4*)(W + (size_t)(k0 + r) * N + n0 + f4 * 4);
    }
    __syncthreads();
    #pragma unroll
    for (int i = 0; i < 4; i++) {
        const int kk = c * 16 + i * 4;
        ushort4 o;
        o.x = f2bf(tile[kk + 0][r]);
        o.y = f2bf(tile[kk + 1][r]);
        o.z = f2bf(tile[kk + 2][r]);
        o.w = f2bf(tile[kk + 3][r]);
        *(ushort4*)(Wt + (size_t)(n0 + r) * K + k0 + kk) = o;
    }
}

// concat bq (1024) + bk (256) -> bqk (1280)
__global__ __launch_bounds__(256) void concat_bias(const float* __restrict__ bq,
        const float* __restrict__ bk, float* __restrict__ bqk) {
    const int i = blockIdx.x * 256 + threadIdx.x;
    if (i < 1024) bqk[i] = bq[i];
    else if (i < 1280) bqk[i] = bk[i - 1024];
}

// ---------------------------------------------------------------------------
// bf16 MFMA GEMM: C[M,N] = A[M,K](bf16) @ Bt[N,K](bf16)^T + bias (+ epilogue)
// BM=128, BN = 128 (waves 2x2, acc 4x4) or 64 (waves 4x1, acc 2x4); BK=32.
// EPI: 0 = bias, 1 = bias+residual (fp32 res), 2 = bias+GELU,
//      3 = bias + transposed V store: C viewed as vt[512][2048],
//          vt[(row>>11)*256 + col][row&2047]  (row=token idx, col=v dim)
// ---------------------------------------------------------------------------
template<int EPI, int BN, typename OutT>
__global__ __launch_bounds__(256) void mgemm(
        const unsigned short* __restrict__ A,   // [M][K] bf16
        const unsigned short* __restrict__ Bt,  // [N][K] bf16
        const float* __restrict__ bias,         // [N]
        const float* __restrict__ res,          // [M][N] fp32 or null
        OutT* __restrict__ C,                   // [M][N] (except EPI3)
        int M, int N, int K) {
    __shared__ __align__(16) unsigned short As[128 * 32];
    __shared__ __align__(16) unsigned short Bs[BN * 32];
    constexpr int MR = (BN == 128) ? 4 : 2;     // m-frags per wave
    constexpr int WM = (BN == 128) ? 64 : 32;   // wave row extent
    const int t = threadIdx.x;
    const int w = t >> 6, l = t & 63;
    const int wr = (BN == 128) ? (w >> 1) : w;
    const int wc = (BN == 128) ? (w & 1) : 0;
    const int li = l & 15, lh = l >> 4;
    const int m0 = blockIdx.y * 128, n0 = blockIdx.x * BN;
    const int lrow = t >> 2, lseg = t & 3;
    const unsigned short* Ag = A  + (size_t)(m0 + lrow) * K + lseg * 8;
    const unsigned short* Bg = Bt + (size_t)(n0 + lrow) * K + lseg * 8;
    unsigned short* Asw = As + w * 512;   // wave chunk base = w*1024B
    unsigned short* Bsw = Bs + w * 512;
    f32x4 acc[MR][4] = {};
    for (int k0 = 0; k0 < K; k0 += 32) {
        __syncthreads();   // previous compute done before LDS overwrite
        gload_lds16(Ag + k0, Asw);
        gload_lds16(Ag + (size_t)64 * K + k0, Asw + 2048);
        gload_lds16(Bg + k0, Bsw);
        if constexpr (BN == 128)
            gload_lds16(Bg + (size_t)64 * K + k0, Bsw + 2048);
        __syncthreads();   // drains vmcnt(0) -> staged data visible
        short8 af[MR], bfr[4];
        #pragma unroll
        for (int m = 0; m < MR; m++)
            af[m] = *(const short8*)&As[(wr * WM + m * 16 + li) * 32 + lh * 8];
        #pragma unroll
        for (int n = 0; n < 4; n++)
            bfr[n] = *(const short8*)&Bs[(wc * 64 + n * 16 + li) * 32 + lh * 8];
        #pragma unroll
        for (int m = 0; m < MR; m++)
            #pragma unroll
            for (int n = 0; n < 4; n++)
                acc[m][n] = __builtin_amdgcn_mfma_f32_16x16x32_bf16(af[m], bfr[n], acc[m][n], 0, 0, 0);
    }
    // epilogue: D[row][col], row = (l>>4)*4 + q, col = l&15 within each 16x16
    #pragma unroll
    for (int n = 0; n < 4; n++) {
        const int col = n0 + wc * 64 + n * 16 + li;
        const float bv = bias[col];
        #pragma unroll
        for (int m = 0; m < MR; m++) {
            const int rbase = m0 + wr * WM + m * 16 + lh * 4;
            #pragma unroll
            for (int q = 0; q < 4; q++) {
                const int row = rbase + q;
                float v = acc[m][n][q] + bv;
                if (EPI == 3) {
                    const size_t tidx = ((size_t)((row >> 11) * 256 + col)) * 2048 + (row & 2047);
                    C[tidx] = (OutT)f2bf(v);
                } else {
                    const size_t idx = (size_t)row * N + col;
                    if (EPI == 1) v += res[idx];
                    if (EPI == 2) v = gelu_exact(v);
                    if constexpr (sizeof(OutT) == 2) C[idx] = (OutT)f2bf(v);
                    else                             C[idx] = v;
                }
            }
        }
    }
}

// ---------------------------------------------------------------------------
// Causal GQA flash attention, bf16 MFMA, double-buffered gload_lds staging.
// Grid: NB*16*(Tt/64); block = 256 threads = 4 waves; wave w owns rows w*16..+16.
// K staged from qk_bf (cols 1024+g*64..) with source-side swizzle; V staged
// from pre-transposed vt_bf[(b*4+g)*64+d][tau]. LDS content layout identical
// to the verified round-6 kernel (elem (r,y) holds col (y>>3 ^ (r&7))*8+(y&7)),
// so the compute section is unchanged. One raw s_barrier + vmcnt(0) per tile;
// next-tile loads issued BEFORE compute stay in flight under it (T3 2-phase).
// ---------------------------------------------------------------------------
__global__ __launch_bounds__(256) void attn_mfma(
        const unsigned short* __restrict__ qkb, // [4096][1280] q:0-1023 k:1024-1279
        const unsigned short* __restrict__ vtb, // [512][2048]  [(b*4+g)*64+d][tau]
        unsigned short* __restrict__ ob) {      // [4096][1024] bf16
    const int blk = blockIdx.x;
    const int qt = 31 - (blk & 31);          // heaviest first
    const int head = (blk >> 5) & 15;
    const int b = blk >> 9;
    const int g = head >> 2;
    const int t = threadIdx.x;
    const int w = t >> 6, l = t & 63;
    const int li = l & 15, lh = l >> 4;
    const int sw = (li & 7) << 3;            // read-side swizzle

    __shared__ __align__(16) unsigned short Ks[2][64 * 64];
    __shared__ __align__(16) unsigned short Vt[2][64 * 64];
    __shared__ __align__(16) unsigned short Pl[4][16 * 64];
    unsigned short* Pw = Pl[w];

    // Q fragments in registers, prescaled by 1/8 (exact in bf16: pow2)
    short8 aq[2];
    {
        const unsigned short* qrow =
            qkb + (size_t)(b * Tt + qt * 64 + w * 16 + li) * 1280 + head * 64;
        #pragma unroll
        for (int s = 0; s < 2; s++) {
            uint4 raw = *(const uint4*)(qrow + s * 32 + lh * 8);
            unsigned short* u = (unsigned short*)&raw;
            #pragma unroll
            for (int j = 0; j < 8; j++) u[j] = f2bf(bf2f(u[j]) * 0.125f);
            aq[s] = *(const short8*)&raw;
        }
    }

    float mrow[4], lrow[4];
    f32x4 acc[4] = {};
    #pragma unroll
    for (int r = 0; r < 4; r++) { mrow[r] = -INFINITY; lrow[r] = 0.0f; }

    // staging lane constants: per call c, wave covers 8 LDS rows (128B each)
    const int srow = l >> 3, sseg = l & 7;
    const unsigned short* kg = qkb + (size_t)b * Tt * 1280 + 1024 + g * 64;
    const unsigned short* vg = vtb + (size_t)((b * 4 + g) * 64) * 2048;

    auto stage = [&](int buf, int tile) {
        #pragma unroll
        for (int c = 0; c < 2; c++) {
            const int rb = (c * 4 + w) * 8;
            const int kr = rb + srow;                   // key row (K) / dim row (V)
            const int sg = (sseg ^ (kr & 7)) * 8;       // source-side swizzle
            gload_lds16(kg + (size_t)(tile * 64 + kr) * 1280 + sg, &Ks[buf][rb * 64]);
            gload_lds16(vg + (size_t)kr * 2048 + tile * 64 + sg,   &Vt[buf][rb * 64]);
        }
    };

    stage(0, 0);
    asm volatile("s_waitcnt vmcnt(0)" ::: "memory");
    __builtin_amdgcn_s_barrier();

    for (int kt = 0; kt <= qt; kt++) {
        const int cur = kt & 1;
        if (kt < qt) stage(cur ^ 1, kt + 1);   // in flight during compute
        const unsigned short* KsB = Ks[cur];
        const unsigned short* VtB = Vt[cur];

        const bool diagt = (kt == qt);
        // ---- QK^T ----
        f32x4 s4[4];
        #pragma unroll
        for (int tile = 0; tile < 4; tile++)
            s4[tile] = (f32x4){-INFINITY, -INFINITY, -INFINITY, -INFINITY};
        #pragma unroll
        for (int tile = 0; tile < 4; tile++) {
            if (diagt && tile > w) continue;     // fully masked for this wave
            f32x4 z = {};
            #pragma unroll
            for (int s = 0; s < 2; s++) {
                short8 bk = *(const short8*)
                    &KsB[(tile * 16 + li) * 64 + ((s * 32 + lh * 8) ^ sw)];
                z = __builtin_amdgcn_mfma_f32_16x16x32_bf16(aq[s], bk, z, 0, 0, 0);
            }
            if (diagt && tile == w) {            // mask key>q on the diagonal
                #pragma unroll
                for (int r = 0; r < 4; r++)
                    if (li > lh * 4 + r) z[r] = -INFINITY;
            }
            s4[tile] = z;
        }
        // ---- online softmax (rows = lh*4+r, shared by the 16 li-lanes) ----
        float mx[4];
        #pragma unroll
        for (int r = 0; r < 4; r++) {
            float v = s4[0][r];
            v = fmaxf(v, s4[1][r]); v = fmaxf(v, s4[2][r]); v = fmaxf(v, s4[3][r]);
            mx[r] = v;
        }
        #pragma unroll
        for (int off = 1; off < 16; off <<= 1)
            #pragma unroll
            for (int r = 0; r < 4; r++)
                mx[r] = fmaxf(mx[r], __shfl_xor(mx[r], off));
        float corr[4];
        #pragma unroll
        for (int r = 0; r < 4; r++) {
            const float nm = fmaxf(mrow[r], mx[r]);   // finite after tile 0
            corr[r] = __expf(mrow[r] - nm);           // -inf -> 0 first time
            mrow[r] = nm;
        }
        float p[4][4], rs[4] = {};
        #pragma unroll
        for (int tile = 0; tile < 4; tile++)
            #pragma unroll
            for (int r = 0; r < 4; r++) {
                const float pv = __expf(s4[tile][r] - mrow[r]);  // exp(-inf)=0
                p[tile][r] = pv;
                rs[r] += pv;
            }
        #pragma unroll
        for (int off = 1; off < 16; off <<= 1)
            #pragma unroll
            for (int r = 0; r < 4; r++)
                rs[r] += __shfl_xor(rs[r], off);
        #pragma unroll
        for (int r = 0; r < 4; r++)
            lrow[r] = lrow[r] * corr[r] + rs[r];
        #pragma unroll
        for (int n = 0; n < 4; n++)
            #pragma unroll
            for (int r = 0; r < 4; r++)
                acc[n][r] *= corr[r];
        // ---- P -> LDS (wave-private; zero for masked tiles) ----
        #pragma unroll
        for (int tile = 0; tile < 4; tile++)
            #pragma unroll
            for (int r = 0; r < 4; r++) {
                const int q = lh * 4 + r;
                Pw[q * 64 + ((tile * 16 + li) ^ ((q & 7) << 3))] = f2bf(p[tile][r]);
            }
        // ---- PV (compiler inserts lgkmcnt for P write->read dependency) ----
        #pragma unroll
        for (int s = 0; s < 2; s++) {
            short8 pa = *(const short8*)&Pw[li * 64 + ((s * 32 + lh * 8) ^ sw)];
            #pragma unroll
            for (int n = 0; n < 4; n++) {
                short8 bv = *(const short8*)
                    &VtB[(n * 16 + li) * 64 + ((s * 32 + lh * 8) ^ sw)];
                acc[n] = __builtin_amdgcn_mfma_f32_16x16x32_bf16(pa, bv, acc[n], 0, 0, 0);
            }
        }
        // next-tile loads landed; all waves done reading cur
        asm volatile("s_waitcnt vmcnt(0)" ::: "memory");
        __builtin_amdgcn_s_barrier();
    }
    // ---- epilogue: out[q][dim] = acc/l ----
    float inv[4];
    #pragma unroll
    for (int r = 0; r < 4; r++) inv[r] = 1.0f / lrow[r];
    unsigned short* orow =
        ob + (size_t)(b * Tt + qt * 64 + w * 16) * Dm + head * 64;
    #pragma unroll
    for (int n = 0; n < 4; n++)
        #pragma unroll
        for (int r = 0; r < 4; r++)
            orow[(size_t)(lh * 4 + r) * Dm + n * 16 + li] = f2bf(acc[n][r] * inv[r]);
}

// ---------------------------------------------------------------------------
extern "C" void kernel_launch(void* const* d_in, const int* in_sizes, int n_in,
                              void* d_out, int out_size, void* d_ws, size_t ws_size,
                              hipStream_t stream) {
    (void)in_sizes; (void)n_in; (void)out_size; (void)ws_size;
    const float* x   = (const float*)d_in[0];
    const float* g1  = (const float*)d_in[1];
    const float* bt1 = (const float*)d_in[2];
    const float* wq  = (const float*)d_in[3];
    const float* bq  = (const float*)d_in[4];
    const float* wk  = (const float*)d_in[5];
    const float* bk  = (const float*)d_in[6];
    const float* wv  = (const float*)d_in[7];
    const float* bv  = (const float*)d_in[8];
    const float* wo  = (const float*)d_in[9];
    const float* bo  = (const float*)d_in[10];
    const float* g2  = (const float*)d_in[11];
    const float* bt2 = (const float*)d_in[12];
    const float* w1  = (const float*)d_in[13];
    const float* b1  = (const float*)d_in[14];
    const float* w2  = (const float*)d_in[15];
    const float* b2  = (const float*)d_in[16];
    float* out = (float*)d_out;

    // workspace layout (bytes)
    char* p = (char*)d_ws;
    unsigned short* h_bf  = (unsigned short*)p; p += (size_t)NROWS * Dm * 2;      // 8 MB
    unsigned short* h2_bf = (unsigned short*)p; p += (size_t)NROWS * Dm * 2;      // 8 MB
    unsigned short* at_bf = (unsigned short*)p; p += (size_t)NROWS * Dm * 2;      // 8 MB
    unsigned short* f1_bf = (unsigned short*)p; p += (size_t)NROWS * 4096 * 2;    // 32 MB
    unsigned short* qk_bf = (unsigned short*)p; p += (size_t)NROWS * 1280 * 2;    // 10 MB
    unsigned short* vt_bf = (unsigned short*)p; p += (size_t)512 * 2048 * 2;      // 2 MB
    unsigned short* wqkT = (unsigned short*)p; p += (size_t)1280 * 1024 * 2;      // 2.5 MB
    unsigned short* wvT  = (unsigned short*)p; p += (size_t)256 * 1024 * 2;
    unsigned short* woT  = (unsigned short*)p; p += (size_t)1024 * 1024 * 2;
    unsigned short* w1T  = (unsigned short*)p; p += (size_t)4096 * 1024 * 2;
    unsigned short* w2T  = (unsigned short*)p; p += (size_t)1024 * 4096 * 2;
    float* bqk = (float*)p; p += 1280 * 4;

    // 0. weight transposes + bf16 convert; bias concat
    transpose_cvt<<<dim3(16, 16), 256, 0, stream>>>(wq, wqkT, 1024, 1024);
    transpose_cvt<<<dim3(16, 4),  256, 0, stream>>>(wk, wqkT + (size_t)1024 * 1024, 1024, 256);
    transpose_cvt<<<dim3(16, 4),  256, 0, stream>>>(wv, wvT, 1024, 256);
    transpose_cvt<<<dim3(16, 16), 256, 0, stream>>>(wo, woT, 1024, 1024);
    transpose_cvt<<<dim3(16, 64), 256, 0, stream>>>(w1, w1T, 1024, 4096);
    transpose_cvt<<<dim3(64, 16), 256, 0, stream>>>(w2, w2T, 4096, 1024);
    concat_bias<<<5, 256, 0, stream>>>(bq, bk, bqk);

    // 1. h = LN1(x) -> bf16
    ln_kernel<<<NROWS, 256, 0, stream>>>(x, g1, bt1, h_bf);
    // 2. fused q|k projection -> qk_bf [4096][1280]
    mgemm<0, 64, unsigned short><<<dim3(20, 32), 256, 0, stream>>>(h_bf, wqkT, bqk, nullptr, qk_bf, NROWS, 1280, 1024);
    // 3. v projection -> transposed vt_bf [512][2048]
    mgemm<3, 64, unsigned short><<<dim3(4, 32), 256, 0, stream>>>(h_bf, wvT, bv, nullptr, vt_bf, NROWS, 256, 1024);
    // 4. attention (bf16 MFMA, dbuf) -> at_bf
    attn_mfma<<<NB * 16 * (Tt / 64), 256, 0, stream>>>(qk_bf, vt_bf, at_bf);
    // 5. x2 = x + attn@wo + bo -> d_out (fp32)
    mgemm<1, 64, float><<<dim3(16, 32), 256, 0, stream>>>(at_bf, woT, bo, x, out, NROWS, 1024, 1024);
    // 6. h2 = LN2(x2) -> bf16
    ln_kernel<<<NROWS, 256, 0, stream>>>(out, g2, bt2, h2_bf);
    // 7. f1 = gelu(h2@w1 + b1) -> bf16
    mgemm<2, 128, unsigned short><<<dim3(32, 32), 256, 0, stream>>>(h2_bf, w1T, b1, nullptr, f1_bf, NROWS, 4096, 1024);
    // 8. out = x2 + f1@w2 + b2 (in-place residual, per-element same-thread RAW)
    mgemm<1, 64, float><<<dim3(16, 32), 256, 0, stream>>>(f1_bf, w2T, b2, out, out, NROWS, 1024, 4096);
}